// Round 9
// baseline (4236.774 us; speedup 1.0000x reference)
//
#include <hip/hip_runtime.h>
#include <hip/hip_bf16.h>

#define N_NODES 50000
#define FEAT    128
#define FP_LEN  2048
#define RADIUS  4
#define N_EDGES 600000
#define BN_EPS  1e-5f

typedef __attribute__((ext_vector_type(8))) short bh8;   // 8 bf16 = 4 VGPR
typedef __attribute__((ext_vector_type(4))) float f32x4;

#define FOR8(M)  M(0) M(1) M(2) M(3) M(4) M(5) M(6) M(7)
#define FOR32(M) M(0) M(1) M(2) M(3) M(4) M(5) M(6) M(7) M(8) M(9) M(10) M(11) \
                 M(12) M(13) M(14) M(15) M(16) M(17) M(18) M(19) M(20) M(21) \
                 M(22) M(23) M(24) M(25) M(26) M(27) M(28) M(29) M(30) M(31)

// B-stream pipeline macros (textually reference BH, BL, base, ah, al, acc)
#define LD1(buf, i, n) { buf[2*(i)] = BH[base + (n) * 256]; \
                         buf[2*(i)+1] = BL[base + (n) * 256]; }
#define LDC(buf, c) LD1(buf, 0, (c)*4) LD1(buf, 1, (c)*4+1) \
                    LD1(buf, 2, (c)*4+2) LD1(buf, 3, (c)*4+3)
#define MF1(buf, i, n) { \
    bh8 bhf = __builtin_bit_cast(bh8, buf[2*(i)]); \
    bh8 blf = __builtin_bit_cast(bh8, buf[2*(i)+1]); \
    f32x4 t = acc[n]; \
    t = __builtin_amdgcn_mfma_f32_16x16x32_bf16(ah, bhf, t, 0, 0, 0); \
    t = __builtin_amdgcn_mfma_f32_16x16x32_bf16(ah, blf, t, 0, 0, 0); \
    t = __builtin_amdgcn_mfma_f32_16x16x32_bf16(al, bhf, t, 0, 0, 0); \
    acc[n] = t; }
#define MFC(buf, c) MF1(buf, 0, (c)*4) MF1(buf, 1, (c)*4+1) \
                    MF1(buf, 2, (c)*4+2) MF1(buf, 3, (c)*4+3)

// round-to-nearest-even fp32 -> bf16 (returns low 16 bits)
__device__ __forceinline__ unsigned bf16_rne(float x) {
    unsigned u = __float_as_uint(x);
    return (u + 0x7fffu + ((u >> 16) & 1u)) >> 16;
}

// split two floats into packed-pair hi/lo bf16 dwords (elem0 = low half)
__device__ __forceinline__ void split2(float x0, float x1, unsigned& hi, unsigned& lo) {
    unsigned h0 = bf16_rne(x0), h1 = bf16_rne(x1);
    float r0 = x0 - __uint_as_float(h0 << 16);
    float r1 = x1 - __uint_as_float(h1 << 16);
    hi = h0 | (h1 << 16);
    lo = bf16_rne(r0) | (bf16_rne(r1) << 16);
}

// Stage X[row0..row0+ROWS) x 128 fp32 -> LDS split bf16 hi/lo, XOR-swizzled
// (byte ^= (row&7)<<4 within each 256B row) for conflict-free b128 frag reads.
template <int ROWS, int NT>
__device__ __forceinline__ void stage_split(const float* __restrict__ X, int row0,
                                            unsigned short* Ahi, unsigned short* Alo,
                                            int t) {
    const int NF4 = ROWS * 32;  // float4 count
    const float4* X4 = (const float4*)(X + (size_t)row0 * FEAT);
    #pragma unroll
    for (int f = t; f < NF4; f += NT) {
        int row = f >> 5, kq = f & 31;  // k = kq*4
        float4 v = make_float4(0.f, 0.f, 0.f, 0.f);
        if (row0 + row < N_NODES) v = X4[f];
        unsigned h0, l0, h1, l1;
        split2(v.x, v.y, h0, l0);
        split2(v.z, v.w, h1, l1);
        int boff = (kq * 8) ^ ((row & 7) << 4);
        unsigned* dh = (unsigned*)((char*)Ahi + row * 256 + boff);
        unsigned* dl = (unsigned*)((char*)Alo + row * 256 + boff);
        dh[0] = h0; dh[1] = h1;
        dl[0] = l0; dl[1] = l1;
    }
}

// ---------------------------------------------------------------------------
// Zero accumulators.
// ---------------------------------------------------------------------------
__global__ __launch_bounds__(256) void k_zero(float* fp, float* stats,
                                              int* counts, int* cursor) {
    int i = blockIdx.x * blockDim.x + threadIdx.x;
    int n = gridDim.x * blockDim.x;
    for (int j = i; j < FP_LEN; j += n) fp[j] = 0.f;
    for (int j = i; j < RADIUS * 2 * FEAT; j += n) stats[j] = 0.f;
    for (int j = i; j < N_NODES; j += n) { counts[j] = 0; cursor[j] = 0; }
}

// ---------------------------------------------------------------------------
// W split+transpose: fp32 [128][N] -> hi/lo bf16 [N][128] (K-contiguous).
// ---------------------------------------------------------------------------
__global__ __launch_bounds__(256) void k_wsplit(
    const float* __restrict__ init_w, const float* __restrict__ soft_w,
    const float* __restrict__ hash_w,
    unsigned* __restrict__ WhiB, unsigned* __restrict__ WloB,
    unsigned* __restrict__ WhiH, unsigned* __restrict__ WloH) {
    __shared__ float Tl[128][65];
    int t = threadIdx.x;
    int y = blockIdx.y;
    const float* W;
    unsigned *Oh, *Ol;
    int N;
    if (y < 5) {
        N = FP_LEN;
        W = (y == 0) ? init_w : soft_w + (size_t)(y - 1) * FEAT * FP_LEN;
        Oh = WhiB + (size_t)y * FP_LEN * (FEAT / 2);
        Ol = WloB + (size_t)y * FP_LEN * (FEAT / 2);
    } else {
        if (blockIdx.x >= 2) return;  // uniform per block
        N = FEAT;
        W = hash_w + (size_t)(y - 5) * FEAT * FEAT;
        Oh = WhiH + (size_t)(y - 5) * FEAT * (FEAT / 2);
        Ol = WloH + (size_t)(y - 5) * FEAT * (FEAT / 2);
    }
    int n0 = blockIdx.x * 64;
    #pragma unroll
    for (int i = 0; i < 8; i++) {
        int f = t + i * 256;  // 0..2047
        int k = f >> 4, nq = f & 15;
        float4 v = *(const float4*)(W + (size_t)k * N + n0 + nq * 4);
        Tl[k][nq * 4 + 0] = v.x; Tl[k][nq * 4 + 1] = v.y;
        Tl[k][nq * 4 + 2] = v.z; Tl[k][nq * 4 + 3] = v.w;
    }
    __syncthreads();
    int nl = t >> 2, kq = t & 3;  // col n0+nl, k-range kq*32..+31
    unsigned hi[16], lo[16];
    #pragma unroll
    for (int d = 0; d < 16; d++) {
        float x0 = Tl[kq * 32 + 2 * d][nl];
        float x1 = Tl[kq * 32 + 2 * d + 1][nl];
        split2(x0, x1, hi[d], lo[d]);
    }
    size_t col = n0 + nl;
    uint4* H = (uint4*)Oh + col * 16 + kq * 4;
    uint4* L = (uint4*)Ol + col * 16 + kq * 4;
    #pragma unroll
    for (int j = 0; j < 4; j++) {
        H[j] = make_uint4(hi[4 * j], hi[4 * j + 1], hi[4 * j + 2], hi[4 * j + 3]);
        L[j] = make_uint4(lo[4 * j], lo[4 * j + 1], lo[4 * j + 2], lo[4 * j + 3]);
    }
}

// ---------------------------------------------------------------------------
// CSR build.
// ---------------------------------------------------------------------------
__global__ __launch_bounds__(256) void k_count(const int* __restrict__ dst,
                                               int* __restrict__ counts) {
    int e = blockIdx.x * 256 + threadIdx.x;
    if (e < N_EDGES) {
        unsigned d = (unsigned)dst[e];
        if (d < N_NODES) atomicAdd(&counts[d], 1);
    }
}

__global__ __launch_bounds__(1024) void k_scan(const int* __restrict__ counts,
                                               int* __restrict__ offs) {
    __shared__ int part[1024];
    int tid = threadIdx.x;
    const int chunk = (N_NODES + 1023) / 1024;
    int lo = tid * chunk;
    int hi = min(lo + chunk, N_NODES);
    int s = 0;
    for (int i = lo; i < hi; i++) s += counts[i];
    part[tid] = s;
    __syncthreads();
    for (int off = 1; off < 1024; off <<= 1) {
        int v = (tid >= off) ? part[tid - off] : 0;
        __syncthreads();
        part[tid] += v;
        __syncthreads();
    }
    int run = part[tid] - s;
    for (int i = lo; i < hi; i++) { offs[i] = run; run += counts[i]; }
    if (lo < N_NODES && hi == N_NODES) offs[N_NODES] = run;
}

__global__ __launch_bounds__(256) void k_fill(const int* __restrict__ src,
                                              const int* __restrict__ dst,
                                              const int* __restrict__ offs,
                                              int* __restrict__ cursor,
                                              int* __restrict__ csr) {
    int e = blockIdx.x * 256 + threadIdx.x;
    if (e < N_EDGES) {
        unsigned d = (unsigned)dst[e];
        unsigned s = (unsigned)src[e];
        if (d < N_NODES && s < N_NODES) {
            int p = atomicAdd(&cursor[d], 1);
            csr[offs[d] + p] = (int)s;
        }
    }
}

// ---------------------------------------------------------------------------
// Aggregation: agg[i] = feats[i] + sum_{e: dst==i} feats[src_e]
// ---------------------------------------------------------------------------
__global__ __launch_bounds__(256) void k_agg(const float* __restrict__ feats,
                                             float* __restrict__ agg,
                                             const int* __restrict__ offs,
                                             const int* __restrict__ csr) {
    int node = blockIdx.x * 4 + (threadIdx.x >> 6);
    int lane = threadIdx.x & 63;
    const float2* f2 = (const float2*)feats;
    float2 acc = f2[node * 64 + lane];
    int j0 = offs[node], j1 = offs[node + 1];
    for (int j = j0; j < j1; j++) {
        int s = csr[j];
        float2 v = f2[s * 64 + lane];
        acc.x += v.x; acc.y += v.y;
    }
    ((float2*)agg)[node * 64 + lane] = acc;
}

// ---------------------------------------------------------------------------
// Hash layer via bf16x3 MFMA: h = relu(agg @ W + b) + fused BN column stats.
// Block: 64 rows x 128 cols, 4 waves (wave = 16 rows x 128 cols), 36 KB LDS.
// __launch_bounds__(256, 2): VGPR cap 256 -> no spill of acc+bufs (~150 regs).
// ---------------------------------------------------------------------------
__global__ __launch_bounds__(256, 2) void k_hash_mfma(
    const float* __restrict__ Xagg,
    const unsigned* __restrict__ WhiT, const unsigned* __restrict__ WloT,
    const float* __restrict__ bias, float* __restrict__ h,
    float* __restrict__ stat_sum, float* __restrict__ stat_sq) {
    __shared__ unsigned short Ahi[64 * FEAT];   // 16 KB
    __shared__ unsigned short Alo[64 * FEAT];   // 16 KB
    __shared__ float colred[2][4][FEAT];        // 4 KB

    int t = threadIdx.x;
    int row0 = blockIdx.x * 64;
    stage_split<64, 256>(Xagg, row0, Ahi, Alo, t);
    __syncthreads();

    int wave = t >> 6, lane = t & 63;
    int g = lane >> 4, q = lane & 15;

    f32x4 acc[8];
#define ZH(n) acc[n] = (f32x4){0.f, 0.f, 0.f, 0.f};
    FOR8(ZH)
#undef ZH

    int arow = wave * 16 + q;
    const uint4* BH = (const uint4*)WhiT;
    const uint4* BL = (const uint4*)WloT;
    uint4 bufA[8], bufB[8];

    for (int s = 0; s < 4; s++) {
        int aoff = arow * 256 + (((s * 64) + (g * 16)) ^ ((arow & 7) << 4));
        bh8 ah = *(const bh8*)((const char*)Ahi + aoff);
        bh8 al = *(const bh8*)((const char*)Alo + aoff);
        int base = q * 16 + g + s * 4;
        LDC(bufA, 0) LDC(bufB, 1)
        MFC(bufA, 0)
        MFC(bufB, 1)
    }

    // epilogue: bias + relu + mask, store h, column stats
    int rbase = row0 + wave * 16 + g * 4;
    float vm0 = (rbase + 0 < N_NODES) ? 1.f : 0.f;
    float vm1 = (rbase + 1 < N_NODES) ? 1.f : 0.f;
    float vm2 = (rbase + 2 < N_NODES) ? 1.f : 0.f;
    float vm3 = (rbase + 3 < N_NODES) ? 1.f : 0.f;
#define EH(n) { int col = (n) * 16 + q; float b = bias[col]; f32x4 tt = acc[n]; \
    float v0 = fmaxf(tt[0] + b, 0.f) * vm0; \
    float v1 = fmaxf(tt[1] + b, 0.f) * vm1; \
    float v2 = fmaxf(tt[2] + b, 0.f) * vm2; \
    float v3 = fmaxf(tt[3] + b, 0.f) * vm3; \
    if (vm0 != 0.f) h[(size_t)(rbase + 0) * FEAT + col] = v0; \
    if (vm1 != 0.f) h[(size_t)(rbase + 1) * FEAT + col] = v1; \
    if (vm2 != 0.f) h[(size_t)(rbase + 2) * FEAT + col] = v2; \
    if (vm3 != 0.f) h[(size_t)(rbase + 3) * FEAT + col] = v3; \
    float cs = v0 + v1 + v2 + v3; \
    float cq = v0 * v0 + v1 * v1 + v2 * v2 + v3 * v3; \
    cs += __shfl_xor(cs, 16); cs += __shfl_xor(cs, 32); \
    cq += __shfl_xor(cq, 16); cq += __shfl_xor(cq, 32); \
    if (g == 0) { colred[0][wave][col] = cs; colred[1][wave][col] = cq; } }
    FOR8(EH)
#undef EH
    __syncthreads();
    if (t < FEAT) {
        float s = 0.f, qq = 0.f;
        #pragma unroll
        for (int w2 = 0; w2 < 4; w2++) { s += colred[0][w2][t]; qq += colred[1][w2][t]; }
        atomicAdd(&stat_sum[t], s);
        atomicAdd(&stat_sq[t], qq);
    }
}

// ---------------------------------------------------------------------------
// BN finalize + apply.
// ---------------------------------------------------------------------------
__global__ void k_finalize(float* stat_sum, float* stat_sq,
                           const float* __restrict__ gamma,
                           const float* __restrict__ beta) {
    int c = threadIdx.x;
    float mu = stat_sum[c] * (1.f / N_NODES);
    float var = stat_sq[c] * (1.f / N_NODES) - mu * mu;
    float sc = gamma[c] * rsqrtf(var + BN_EPS);
    float sh = beta[c] - mu * sc;
    stat_sum[c] = sc;
    stat_sq[c] = sh;
}

__global__ __launch_bounds__(256) void k_bnapply(float* __restrict__ h,
                                                 const float* __restrict__ scale,
                                                 const float* __restrict__ shift) {
    int i = blockIdx.x * 256 + threadIdx.x;
    const float4* sc4 = (const float4*)scale;
    const float4* sh4 = (const float4*)shift;
    if (i < N_NODES * 32) {
        float4 v = ((float4*)h)[i];
        int cb = i & 31;
        float4 s = sc4[cb], b = sh4[cb];
        v.x = v.x * s.x + b.x;
        v.y = v.y * s.y + b.y;
        v.z = v.z * s.z + b.z;
        v.w = v.w * s.w + b.w;
        ((float4*)h)[i] = v;
    }
}

// ---------------------------------------------------------------------------
// Fused softmax-sum GEMM via bf16x3 MFMA.
// Block: 32 rows x 2048 cols, 8 waves = 2 rowgrp x 4 colgrp.
// Wave: 16 rows x 512 cols = 32 subtiles; acc fully macro-expanded (static
// register indices), B streamed via 2-chunk double-buffered reg pipeline.
// __launch_bounds__(512, 2): 8 waves/block = 2 waves/EU -> VGPR cap 256/wave,
// so the ~232 live regs (acc 128 + bufs 64 + frags/addr) allocate WITHOUT
// spill. Resulting occupancy: 2 waves/SIMD, 1 block/CU; latency hidden by the
// 16-deep in-register B pipeline + 2-wave TLP.
// C layout (m89): col = lane&15 (+n*16+cg*512), row = (lane>>4)*4 + reg.
// ---------------------------------------------------------------------------
__global__ __launch_bounds__(512, 2) void k_smgemm_mfma(
    const float* __restrict__ X,
    const unsigned* __restrict__ WhiT, const unsigned* __restrict__ WloT,
    const float* __restrict__ bias, float* __restrict__ fp) {
    __shared__ unsigned short Ahi[32 * FEAT];  // 8 KB
    __shared__ unsigned short Alo[32 * FEAT];  // 8 KB
    __shared__ float fpacc[FP_LEN];            // 8 KB
    __shared__ float red[32 * 4];

    int t = threadIdx.x;
    int row0 = blockIdx.x * 32;

    #pragma unroll
    for (int i = 0; i < 4; i++) fpacc[t + i * 512] = 0.f;

    stage_split<32, 512>(X, row0, Ahi, Alo, t);
    __syncthreads();

    int wave = t >> 6, lane = t & 63;
    int rg = wave >> 2, cg = wave & 3;
    int g = lane >> 4, q = lane & 15;

    f32x4 acc[32];
#define ZZ(n) acc[n] = (f32x4){0.f, 0.f, 0.f, 0.f};
    FOR32(ZZ)
#undef ZZ

    int arow = rg * 16 + q;
    const uint4* BH = (const uint4*)WhiT;
    const uint4* BL = (const uint4*)WloT;
    int bbase = (cg * 512 + q) * 16 + g;  // [col][k] uint4 units; +n*256, +s*4
    uint4 bufA[8], bufB[8];

    for (int s = 0; s < 4; s++) {
        int aoff = arow * 256 + (((s * 64) + (g * 16)) ^ ((arow & 7) << 4));
        bh8 ah = *(const bh8*)((const char*)Ahi + aoff);
        bh8 al = *(const bh8*)((const char*)Alo + aoff);
        int base = bbase + s * 4;
        LDC(bufA, 0) LDC(bufB, 1)
        MFC(bufA, 0) LDC(bufA, 2)
        MFC(bufB, 1) LDC(bufB, 3)
        MFC(bufA, 2) LDC(bufA, 4)
        MFC(bufB, 3) LDC(bufB, 5)
        MFC(bufA, 4) LDC(bufA, 6)
        MFC(bufB, 5) LDC(bufB, 7)
        MFC(bufA, 6)
        MFC(bufB, 7)
    }

    // ---- softmax epilogue (logits fully in registers) ----
    int colb = cg * 512 + q;
    float m0 = -3.4e38f, m1 = -3.4e38f, m2 = -3.4e38f, m3 = -3.4e38f;
#define BM(n) { float b = bias[colb + (n) * 16]; f32x4 tt = acc[n]; \
    tt[0] += b; tt[1] += b; tt[2] += b; tt[3] += b; \
    m0 = fmaxf(m0, tt[0]); m1 = fmaxf(m1, tt[1]); \
    m2 = fmaxf(m2, tt[2]); m3 = fmaxf(m3, tt[3]); acc[n] = tt; }
    FOR32(BM)
#undef BM
    // row max across q-lanes (cols), then across the 4 col-group waves
    m0 = fmaxf(m0, __shfl_xor(m0, 1)); m0 = fmaxf(m0, __shfl_xor(m0, 2));
    m0 = fmaxf(m0, __shfl_xor(m0, 4)); m0 = fmaxf(m0, __shfl_xor(m0, 8));
    m1 = fmaxf(m1, __shfl_xor(m1, 1)); m1 = fmaxf(m1, __shfl_xor(m1, 2));
    m1 = fmaxf(m1, __shfl_xor(m1, 4)); m1 = fmaxf(m1, __shfl_xor(m1, 8));
    m2 = fmaxf(m2, __shfl_xor(m2, 1)); m2 = fmaxf(m2, __shfl_xor(m2, 2));
    m2 = fmaxf(m2, __shfl_xor(m2, 4)); m2 = fmaxf(m2, __shfl_xor(m2, 8));
    m3 = fmaxf(m3, __shfl_xor(m3, 1)); m3 = fmaxf(m3, __shfl_xor(m3, 2));
    m3 = fmaxf(m3, __shfl_xor(m3, 4)); m3 = fmaxf(m3, __shfl_xor(m3, 8));
    int rrow = rg * 16 + g * 4;
    if (q == 0) {
        red[(rrow + 0) * 4 + cg] = m0;
        red[(rrow + 1) * 4 + cg] = m1;
        red[(rrow + 2) * 4 + cg] = m2;
        red[(rrow + 3) * 4 + cg] = m3;
    }
    __syncthreads();
    {
        const float* r0 = &red[(rrow + 0) * 4];
        const float* r1 = &red[(rrow + 1) * 4];
        const float* r2 = &red[(rrow + 2) * 4];
        const float* r3 = &red[(rrow + 3) * 4];
        m0 = fmaxf(fmaxf(r0[0], r0[1]), fmaxf(r0[2], r0[3]));
        m1 = fmaxf(fmaxf(r1[0], r1[1]), fmaxf(r1[2], r1[3]));
        m2 = fmaxf(fmaxf(r2[0], r2[1]), fmaxf(r2[2], r2[3]));
        m3 = fmaxf(fmaxf(r3[0], r3[1]), fmaxf(r3[2], r3[3]));
    }
    __syncthreads();  // red reads done before sum-partial writes

    float s0 = 0.f, s1 = 0.f, s2 = 0.f, s3 = 0.f;
#define EX(n) { f32x4 tt = acc[n]; \
    tt[0] = __expf(tt[0] - m0); s0 += tt[0]; \
    tt[1] = __expf(tt[1] - m1); s1 += tt[1]; \
    tt[2] = __expf(tt[2] - m2); s2 += tt[2]; \
    tt[3] = __expf(tt[3] - m3); s3 += tt[3]; acc[n] = tt; }
    FOR32(EX)
#undef EX
    s0 += __shfl_xor(s0, 1); s0 += __shfl_xor(s0, 2);
    s0 += __shfl_xor(s0, 4); s0 += __shfl_xor(s0, 8);
    s1 += __shfl_xor(s1, 1); s1 += __shfl_xor(s1, 2);
    s1 += __shfl_xor(s1, 4); s1 += __shfl_xor(s1, 8);
    s2 += __shfl_xor(s2, 1); s2 += __shfl_xor(s2, 2);
    s2 += __shfl_xor(s2, 4); s2 += __shfl_xor(s2, 8);
    s3 += __shfl_xor(s3, 1); s3 += __shfl_xor(s3, 2);
    s3 += __shfl_xor(s3, 4); s3 += __shfl_xor(s3, 8);
    if (q == 0) {
        red[(rrow + 0) * 4 + cg] = s0;
        red[(rrow + 1) * 4 + cg] = s1;
        red[(rrow + 2) * 4 + cg] = s2;
        red[(rrow + 3) * 4 + cg] = s3;
    }
    __syncthreads();
    float iz0, iz1, iz2, iz3;
    {
        const float* r0 = &red[(rrow + 0) * 4];
        const float* r1 = &red[(rrow + 1) * 4];
        const float* r2 = &red[(rrow + 2) * 4];
        const float* r3 = &red[(rrow + 3) * 4];
        int rowg = row0 + rrow;
        iz0 = (rowg + 0 < N_NODES ? 1.f : 0.f) / (r0[0] + r0[1] + r0[2] + r0[3]);
        iz1 = (rowg + 1 < N_NODES ? 1.f : 0.f) / (r1[0] + r1[1] + r1[2] + r1[3]);
        iz2 = (rowg + 2 < N_NODES ? 1.f : 0.f) / (r2[0] + r2[1] + r2[2] + r2[3]);
        iz3 = (rowg + 3 < N_NODES ? 1.f : 0.f) / (r3[0] + r3[1] + r3[2] + r3[3]);
    }
#define CS(n) { f32x4 tt = acc[n]; \
    float cv = tt[0] * iz0 + tt[1] * iz1 + tt[2] * iz2 + tt[3] * iz3; \
    cv += __shfl_xor(cv, 16); cv += __shfl_xor(cv, 32); \
    if (g == 0) atomicAdd(&fpacc[colb + (n) * 16], cv); }
    FOR32(CS)
#undef CS
    __syncthreads();
    #pragma unroll
    for (int i = 0; i < 4; i++) {
        int cidx = t + i * 512;
        atomicAdd(&fp[cidx], fpacc[cidx]);
    }
}

// ---------------------------------------------------------------------------
// Launch
// ---------------------------------------------------------------------------
extern "C" void kernel_launch(void* const* d_in, const int* in_sizes, int n_in,
                              void* d_out, int out_size, void* d_ws, size_t ws_size,
                              hipStream_t stream) {
    const float* atoms  = (const float*)d_in[0];
    const int*   eidx   = (const int*)d_in[1];
    const float* init_w = (const float*)d_in[2];
    const float* init_b = (const float*)d_in[3];
    const float* hash_w = (const float*)d_in[4];
    const float* hash_b = (const float*)d_in[5];
    const float* soft_w = (const float*)d_in[6];
    const float* soft_b = (const float*)d_in[7];
    const float* gamma  = (const float*)d_in[8];
    const float* beta   = (const float*)d_in[9];
    float* fp = (float*)d_out;

    char* ws = (char*)d_ws;
    float* F      = (float*)ws; ws += (size_t)N_NODES * FEAT * 4;
    float* A      = (float*)ws; ws += (size_t)N_NODES * FEAT * 4;
    int*   counts = (int*)ws;   ws += (size_t)N_NODES * 4;
    int*   cursor = (int*)ws;   ws += (size_t)N_NODES * 4;
    int*   offs   = (int*)ws;   ws += (size_t)(N_NODES + 4) * 4;
    int*   csr    = (int*)ws;   ws += (size_t)N_EDGES * 4;
    float* stats  = (float*)ws; ws += (size_t)RADIUS * 2 * FEAT * 4;
    unsigned* WhiB = (unsigned*)ws; ws += (size_t)5 * FP_LEN * (FEAT / 2) * 4;
    unsigned* WloB = (unsigned*)ws; ws += (size_t)5 * FP_LEN * (FEAT / 2) * 4;
    unsigned* WhiH = (unsigned*)ws; ws += (size_t)RADIUS * FEAT * (FEAT / 2) * 4;
    unsigned* WloH = (unsigned*)ws; ws += (size_t)RADIUS * FEAT * (FEAT / 2) * 4;

    const int* src = eidx;
    const int* dst = eidx + N_EDGES;

    k_zero<<<256, 256, 0, stream>>>(fp, stats, counts, cursor);
    k_wsplit<<<dim3(32, 9), 256, 0, stream>>>(init_w, soft_w, hash_w,
                                              WhiB, WloB, WhiH, WloH);
    k_count<<<(N_EDGES + 255) / 256, 256, 0, stream>>>(dst, counts);
    k_scan<<<1, 1024, 0, stream>>>(counts, offs);
    k_fill<<<(N_EDGES + 255) / 256, 256, 0, stream>>>(src, dst, offs, cursor, csr);

    const int SMG = (N_NODES + 31) / 32;    // 1563
    const int HG  = (N_NODES + 63) / 64;    // 782

    k_smgemm_mfma<<<SMG, 512, 0, stream>>>(atoms, WhiB, WloB, init_b, fp);

    const float* feats = atoms;
    for (int l = 0; l < RADIUS; l++) {
        k_agg<<<N_NODES / 4, 256, 0, stream>>>(feats, A, offs, csr);
        float* ss = stats + l * 2 * FEAT;
        float* sq = ss + FEAT;
        k_hash_mfma<<<HG, 256, 0, stream>>>(
            A, WhiH + (size_t)l * FEAT * (FEAT / 2),
            WloH + (size_t)l * FEAT * (FEAT / 2),
            hash_b + (size_t)l * FEAT, F, ss, sq);
        k_finalize<<<1, FEAT, 0, stream>>>(ss, sq, gamma, beta);
        k_bnapply<<<(N_NODES * 32 + 255) / 256, 256, 0, stream>>>(F, ss, sq);
        k_smgemm_mfma<<<SMG, 512, 0, stream>>>(
            F, WhiB + (size_t)(1 + l) * FP_LEN * (FEAT / 2),
            WloB + (size_t)(1 + l) * FP_LEN * (FEAT / 2),
            soft_b + (size_t)l * FP_LEN, fp);
        feats = F;
    }
}

// Round 11
// 4228.062 us; speedup vs baseline: 1.0021x; 1.0021x over previous
//
#include <hip/hip_runtime.h>
#include <hip/hip_bf16.h>

#define N_NODES 50000
#define FEAT    128
#define FP_LEN  2048
#define RADIUS  4
#define N_EDGES 600000
#define BN_EPS  1e-5f

typedef __attribute__((ext_vector_type(8))) short bh8;   // 8 bf16 = 4 VGPR
typedef __attribute__((ext_vector_type(4))) float f32x4;

#define FOR8(M)  M(0) M(1) M(2) M(3) M(4) M(5) M(6) M(7)
#define FOR32(M) M(0) M(1) M(2) M(3) M(4) M(5) M(6) M(7) M(8) M(9) M(10) M(11) \
                 M(12) M(13) M(14) M(15) M(16) M(17) M(18) M(19) M(20) M(21) \
                 M(22) M(23) M(24) M(25) M(26) M(27) M(28) M(29) M(30) M(31)

// B-stream pipeline macros (textually reference BH, BL, base, ah, al, acc)
#define LD1(buf, i, n) { buf[2*(i)] = BH[base + (n) * 256]; \
                         buf[2*(i)+1] = BL[base + (n) * 256]; }
#define LDC(buf, c) LD1(buf, 0, (c)*4) LD1(buf, 1, (c)*4+1) \
                    LD1(buf, 2, (c)*4+2) LD1(buf, 3, (c)*4+3)
#define MF1(buf, i, n) { \
    bh8 bhf = __builtin_bit_cast(bh8, buf[2*(i)]); \
    bh8 blf = __builtin_bit_cast(bh8, buf[2*(i)+1]); \
    f32x4 t = acc[n]; \
    t = __builtin_amdgcn_mfma_f32_16x16x32_bf16(ah, bhf, t, 0, 0, 0); \
    t = __builtin_amdgcn_mfma_f32_16x16x32_bf16(ah, blf, t, 0, 0, 0); \
    t = __builtin_amdgcn_mfma_f32_16x16x32_bf16(al, bhf, t, 0, 0, 0); \
    acc[n] = t; }
#define MFC(buf, c) MF1(buf, 0, (c)*4) MF1(buf, 1, (c)*4+1) \
                    MF1(buf, 2, (c)*4+2) MF1(buf, 3, (c)*4+3)

// round-to-nearest-even fp32 -> bf16 (returns low 16 bits)
__device__ __forceinline__ unsigned bf16_rne(float x) {
    unsigned u = __float_as_uint(x);
    return (u + 0x7fffu + ((u >> 16) & 1u)) >> 16;
}

// split two floats into packed-pair hi/lo bf16 dwords (elem0 = low half)
__device__ __forceinline__ void split2(float x0, float x1, unsigned& hi, unsigned& lo) {
    unsigned h0 = bf16_rne(x0), h1 = bf16_rne(x1);
    float r0 = x0 - __uint_as_float(h0 << 16);
    float r1 = x1 - __uint_as_float(h1 << 16);
    hi = h0 | (h1 << 16);
    lo = bf16_rne(r0) | (bf16_rne(r1) << 16);
}

// Stage X[row0..row0+ROWS) x 128 fp32 -> LDS split bf16 hi/lo, XOR-swizzled
// (byte ^= (row&7)<<4 within each 256B row) for conflict-free b128 frag reads.
template <int ROWS, int NT>
__device__ __forceinline__ void stage_split(const float* __restrict__ X, int row0,
                                            unsigned short* Ahi, unsigned short* Alo,
                                            int t) {
    const int NF4 = ROWS * 32;  // float4 count
    const float4* X4 = (const float4*)(X + (size_t)row0 * FEAT);
    #pragma unroll
    for (int f = t; f < NF4; f += NT) {
        int row = f >> 5, kq = f & 31;  // k = kq*4
        float4 v = make_float4(0.f, 0.f, 0.f, 0.f);
        if (row0 + row < N_NODES) v = X4[f];
        unsigned h0, l0, h1, l1;
        split2(v.x, v.y, h0, l0);
        split2(v.z, v.w, h1, l1);
        int boff = (kq * 8) ^ ((row & 7) << 4);
        unsigned* dh = (unsigned*)((char*)Ahi + row * 256 + boff);
        unsigned* dl = (unsigned*)((char*)Alo + row * 256 + boff);
        dh[0] = h0; dh[1] = h1;
        dl[0] = l0; dl[1] = l1;
    }
}

// ---------------------------------------------------------------------------
// Zero accumulators.
// ---------------------------------------------------------------------------
__global__ __launch_bounds__(256) void k_zero(float* fp, float* stats,
                                              int* counts, int* cursor) {
    int i = blockIdx.x * blockDim.x + threadIdx.x;
    int n = gridDim.x * blockDim.x;
    for (int j = i; j < FP_LEN; j += n) fp[j] = 0.f;
    for (int j = i; j < RADIUS * 2 * FEAT; j += n) stats[j] = 0.f;
    for (int j = i; j < N_NODES; j += n) { counts[j] = 0; cursor[j] = 0; }
}

// ---------------------------------------------------------------------------
// W split+transpose: fp32 [128][N] -> hi/lo bf16 [N][128] (K-contiguous).
// ---------------------------------------------------------------------------
__global__ __launch_bounds__(256) void k_wsplit(
    const float* __restrict__ init_w, const float* __restrict__ soft_w,
    const float* __restrict__ hash_w,
    unsigned* __restrict__ WhiB, unsigned* __restrict__ WloB,
    unsigned* __restrict__ WhiH, unsigned* __restrict__ WloH) {
    __shared__ float Tl[128][65];
    int t = threadIdx.x;
    int y = blockIdx.y;
    const float* W;
    unsigned *Oh, *Ol;
    int N;
    if (y < 5) {
        N = FP_LEN;
        W = (y == 0) ? init_w : soft_w + (size_t)(y - 1) * FEAT * FP_LEN;
        Oh = WhiB + (size_t)y * FP_LEN * (FEAT / 2);
        Ol = WloB + (size_t)y * FP_LEN * (FEAT / 2);
    } else {
        if (blockIdx.x >= 2) return;  // uniform per block
        N = FEAT;
        W = hash_w + (size_t)(y - 5) * FEAT * FEAT;
        Oh = WhiH + (size_t)(y - 5) * FEAT * (FEAT / 2);
        Ol = WloH + (size_t)(y - 5) * FEAT * (FEAT / 2);
    }
    int n0 = blockIdx.x * 64;
    #pragma unroll
    for (int i = 0; i < 8; i++) {
        int f = t + i * 256;  // 0..2047
        int k = f >> 4, nq = f & 15;
        float4 v = *(const float4*)(W + (size_t)k * N + n0 + nq * 4);
        Tl[k][nq * 4 + 0] = v.x; Tl[k][nq * 4 + 1] = v.y;
        Tl[k][nq * 4 + 2] = v.z; Tl[k][nq * 4 + 3] = v.w;
    }
    __syncthreads();
    int nl = t >> 2, kq = t & 3;  // col n0+nl, k-range kq*32..+31
    unsigned hi[16], lo[16];
    #pragma unroll
    for (int d = 0; d < 16; d++) {
        float x0 = Tl[kq * 32 + 2 * d][nl];
        float x1 = Tl[kq * 32 + 2 * d + 1][nl];
        split2(x0, x1, hi[d], lo[d]);
    }
    size_t col = n0 + nl;
    uint4* H = (uint4*)Oh + col * 16 + kq * 4;
    uint4* L = (uint4*)Ol + col * 16 + kq * 4;
    #pragma unroll
    for (int j = 0; j < 4; j++) {
        H[j] = make_uint4(hi[4 * j], hi[4 * j + 1], hi[4 * j + 2], hi[4 * j + 3]);
        L[j] = make_uint4(lo[4 * j], lo[4 * j + 1], lo[4 * j + 2], lo[4 * j + 3]);
    }
}

// ---------------------------------------------------------------------------
// CSR build.
// ---------------------------------------------------------------------------
__global__ __launch_bounds__(256) void k_count(const int* __restrict__ dst,
                                               int* __restrict__ counts) {
    int e = blockIdx.x * 256 + threadIdx.x;
    if (e < N_EDGES) {
        unsigned d = (unsigned)dst[e];
        if (d < N_NODES) atomicAdd(&counts[d], 1);
    }
}

__global__ __launch_bounds__(1024) void k_scan(const int* __restrict__ counts,
                                               int* __restrict__ offs) {
    __shared__ int part[1024];
    int tid = threadIdx.x;
    const int chunk = (N_NODES + 1023) / 1024;
    int lo = tid * chunk;
    int hi = min(lo + chunk, N_NODES);
    int s = 0;
    for (int i = lo; i < hi; i++) s += counts[i];
    part[tid] = s;
    __syncthreads();
    for (int off = 1; off < 1024; off <<= 1) {
        int v = (tid >= off) ? part[tid - off] : 0;
        __syncthreads();
        part[tid] += v;
        __syncthreads();
    }
    int run = part[tid] - s;
    for (int i = lo; i < hi; i++) { offs[i] = run; run += counts[i]; }
    if (lo < N_NODES && hi == N_NODES) offs[N_NODES] = run;
}

__global__ __launch_bounds__(256) void k_fill(const int* __restrict__ src,
                                              const int* __restrict__ dst,
                                              const int* __restrict__ offs,
                                              int* __restrict__ cursor,
                                              int* __restrict__ csr) {
    int e = blockIdx.x * 256 + threadIdx.x;
    if (e < N_EDGES) {
        unsigned d = (unsigned)dst[e];
        unsigned s = (unsigned)src[e];
        if (d < N_NODES && s < N_NODES) {
            int p = atomicAdd(&cursor[d], 1);
            csr[offs[d] + p] = (int)s;
        }
    }
}

// ---------------------------------------------------------------------------
// Aggregation: agg[i] = feats[i] + sum_{e: dst==i} feats[src_e]
// ---------------------------------------------------------------------------
__global__ __launch_bounds__(256) void k_agg(const float* __restrict__ feats,
                                             float* __restrict__ agg,
                                             const int* __restrict__ offs,
                                             const int* __restrict__ csr) {
    int node = blockIdx.x * 4 + (threadIdx.x >> 6);
    int lane = threadIdx.x & 63;
    const float2* f2 = (const float2*)feats;
    float2 acc = f2[node * 64 + lane];
    int j0 = offs[node], j1 = offs[node + 1];
    for (int j = j0; j < j1; j++) {
        int s = csr[j];
        float2 v = f2[s * 64 + lane];
        acc.x += v.x; acc.y += v.y;
    }
    ((float2*)agg)[node * 64 + lane] = acc;
}

// ---------------------------------------------------------------------------
// Hash layer via bf16x3 MFMA: h = relu(agg @ W + b) + fused BN column stats.
// Block: 64 rows x 128 cols, 4 waves (wave = 16 rows x 128 cols), 36 KB LDS.
// (256, 2) decodes to 2 waves/EU under EITHER launch_bounds semantics ->
// VGPR cap 256; demand ~150, no spill.
// ---------------------------------------------------------------------------
__global__ __launch_bounds__(256, 2) void k_hash_mfma(
    const float* __restrict__ Xagg,
    const unsigned* __restrict__ WhiT, const unsigned* __restrict__ WloT,
    const float* __restrict__ bias, float* __restrict__ h,
    float* __restrict__ stat_sum, float* __restrict__ stat_sq) {
    __shared__ unsigned short Ahi[64 * FEAT];   // 16 KB
    __shared__ unsigned short Alo[64 * FEAT];   // 16 KB
    __shared__ float colred[2][4][FEAT];        // 4 KB

    int t = threadIdx.x;
    int row0 = blockIdx.x * 64;
    stage_split<64, 256>(Xagg, row0, Ahi, Alo, t);
    __syncthreads();

    int wave = t >> 6, lane = t & 63;
    int g = lane >> 4, q = lane & 15;

    f32x4 acc[8];
#define ZH(n) acc[n] = (f32x4){0.f, 0.f, 0.f, 0.f};
    FOR8(ZH)
#undef ZH

    int arow = wave * 16 + q;
    const uint4* BH = (const uint4*)WhiT;
    const uint4* BL = (const uint4*)WloT;
    uint4 bufA[8], bufB[8];

    for (int s = 0; s < 4; s++) {
        int aoff = arow * 256 + (((s * 64) + (g * 16)) ^ ((arow & 7) << 4));
        bh8 ah = *(const bh8*)((const char*)Ahi + aoff);
        bh8 al = *(const bh8*)((const char*)Alo + aoff);
        int base = q * 16 + g + s * 4;
        LDC(bufA, 0) LDC(bufB, 1)
        MFC(bufA, 0)
        MFC(bufB, 1)
    }

    // epilogue: bias + relu + mask, store h, column stats
    int rbase = row0 + wave * 16 + g * 4;
    float vm0 = (rbase + 0 < N_NODES) ? 1.f : 0.f;
    float vm1 = (rbase + 1 < N_NODES) ? 1.f : 0.f;
    float vm2 = (rbase + 2 < N_NODES) ? 1.f : 0.f;
    float vm3 = (rbase + 3 < N_NODES) ? 1.f : 0.f;
#define EH(n) { int col = (n) * 16 + q; float b = bias[col]; f32x4 tt = acc[n]; \
    float v0 = fmaxf(tt[0] + b, 0.f) * vm0; \
    float v1 = fmaxf(tt[1] + b, 0.f) * vm1; \
    float v2 = fmaxf(tt[2] + b, 0.f) * vm2; \
    float v3 = fmaxf(tt[3] + b, 0.f) * vm3; \
    if (vm0 != 0.f) h[(size_t)(rbase + 0) * FEAT + col] = v0; \
    if (vm1 != 0.f) h[(size_t)(rbase + 1) * FEAT + col] = v1; \
    if (vm2 != 0.f) h[(size_t)(rbase + 2) * FEAT + col] = v2; \
    if (vm3 != 0.f) h[(size_t)(rbase + 3) * FEAT + col] = v3; \
    float cs = v0 + v1 + v2 + v3; \
    float cq = v0 * v0 + v1 * v1 + v2 * v2 + v3 * v3; \
    cs += __shfl_xor(cs, 16); cs += __shfl_xor(cs, 32); \
    cq += __shfl_xor(cq, 16); cq += __shfl_xor(cq, 32); \
    if (g == 0) { colred[0][wave][col] = cs; colred[1][wave][col] = cq; } }
    FOR8(EH)
#undef EH
    __syncthreads();
    if (t < FEAT) {
        float s = 0.f, qq = 0.f;
        #pragma unroll
        for (int w2 = 0; w2 < 4; w2++) { s += colred[0][w2][t]; qq += colred[1][w2][t]; }
        atomicAdd(&stat_sum[t], s);
        atomicAdd(&stat_sq[t], qq);
    }
}

// ---------------------------------------------------------------------------
// BN finalize + apply.
// ---------------------------------------------------------------------------
__global__ void k_finalize(float* stat_sum, float* stat_sq,
                           const float* __restrict__ gamma,
                           const float* __restrict__ beta) {
    int c = threadIdx.x;
    float mu = stat_sum[c] * (1.f / N_NODES);
    float var = stat_sq[c] * (1.f / N_NODES) - mu * mu;
    float sc = gamma[c] * rsqrtf(var + BN_EPS);
    float sh = beta[c] - mu * sc;
    stat_sum[c] = sc;
    stat_sq[c] = sh;
}

__global__ __launch_bounds__(256) void k_bnapply(float* __restrict__ h,
                                                 const float* __restrict__ scale,
                                                 const float* __restrict__ shift) {
    int i = blockIdx.x * 256 + threadIdx.x;
    const float4* sc4 = (const float4*)scale;
    const float4* sh4 = (const float4*)shift;
    if (i < N_NODES * 32) {
        float4 v = ((float4*)h)[i];
        int cb = i & 31;
        float4 s = sc4[cb], b = sh4[cb];
        v.x = v.x * s.x + b.x;
        v.y = v.y * s.y + b.y;
        v.z = v.z * s.z + b.z;
        v.w = v.w * s.w + b.w;
        ((float4*)h)[i] = v;
    }
}

// ---------------------------------------------------------------------------
// Fused softmax-sum GEMM via bf16x3 MFMA.
// Block: 32 rows x 2048 cols, 8 waves = 2 rowgrp x 4 colgrp.
// Wave: 16 rows x 512 cols = 32 subtiles; acc fully macro-expanded (static
// register indices), B streamed via 2-chunk double-buffered reg pipeline.
//
// __launch_bounds__(512, 1): round-9 PMC showed hipcc decodes the 2nd arg
// with CUDA semantics (min BLOCKS per CU): (512,2) -> 16 waves/CU -> 4
// waves/SIMD -> VGPR cap 512/4 = 128 (measured VGPR_Count=128, 927 MB spill
// traffic). (512,1) -> 8 waves/CU -> 2 waves/SIMD -> cap 512/2 = 256, which
// fits the ~232 live regs (acc 128 + bufs 64 + frags/addr) with NO spill.
// C layout (m89): col = lane&15 (+n*16+cg*512), row = (lane>>4)*4 + reg.
// ---------------------------------------------------------------------------
__global__ __launch_bounds__(512, 1) void k_smgemm_mfma(
    const float* __restrict__ X,
    const unsigned* __restrict__ WhiT, const unsigned* __restrict__ WloT,
    const float* __restrict__ bias, float* __restrict__ fp) {
    __shared__ unsigned short Ahi[32 * FEAT];  // 8 KB
    __shared__ unsigned short Alo[32 * FEAT];  // 8 KB
    __shared__ float fpacc[FP_LEN];            // 8 KB
    __shared__ float red[32 * 4];

    int t = threadIdx.x;
    int row0 = blockIdx.x * 32;

    #pragma unroll
    for (int i = 0; i < 4; i++) fpacc[t + i * 512] = 0.f;

    stage_split<32, 512>(X, row0, Ahi, Alo, t);
    __syncthreads();

    int wave = t >> 6, lane = t & 63;
    int rg = wave >> 2, cg = wave & 3;
    int g = lane >> 4, q = lane & 15;

    f32x4 acc[32];
#define ZZ(n) acc[n] = (f32x4){0.f, 0.f, 0.f, 0.f};
    FOR32(ZZ)
#undef ZZ

    int arow = rg * 16 + q;
    const uint4* BH = (const uint4*)WhiT;
    const uint4* BL = (const uint4*)WloT;
    int bbase = (cg * 512 + q) * 16 + g;  // [col][k] uint4 units; +n*256, +s*4
    uint4 bufA[8], bufB[8];

    for (int s = 0; s < 4; s++) {
        int aoff = arow * 256 + (((s * 64) + (g * 16)) ^ ((arow & 7) << 4));
        bh8 ah = *(const bh8*)((const char*)Ahi + aoff);
        bh8 al = *(const bh8*)((const char*)Alo + aoff);
        int base = bbase + s * 4;
        LDC(bufA, 0) LDC(bufB, 1)
        MFC(bufA, 0) LDC(bufA, 2)
        MFC(bufB, 1) LDC(bufB, 3)
        MFC(bufA, 2) LDC(bufA, 4)
        MFC(bufB, 3) LDC(bufB, 5)
        MFC(bufA, 4) LDC(bufA, 6)
        MFC(bufB, 5) LDC(bufB, 7)
        MFC(bufA, 6)
        MFC(bufB, 7)
    }

    // ---- softmax epilogue (logits fully in registers) ----
    int colb = cg * 512 + q;
    float m0 = -3.4e38f, m1 = -3.4e38f, m2 = -3.4e38f, m3 = -3.4e38f;
#define BM(n) { float b = bias[colb + (n) * 16]; f32x4 tt = acc[n]; \
    tt[0] += b; tt[1] += b; tt[2] += b; tt[3] += b; \
    m0 = fmaxf(m0, tt[0]); m1 = fmaxf(m1, tt[1]); \
    m2 = fmaxf(m2, tt[2]); m3 = fmaxf(m3, tt[3]); acc[n] = tt; }
    FOR32(BM)
#undef BM
    // row max across q-lanes (cols), then across the 4 col-group waves
    m0 = fmaxf(m0, __shfl_xor(m0, 1)); m0 = fmaxf(m0, __shfl_xor(m0, 2));
    m0 = fmaxf(m0, __shfl_xor(m0, 4)); m0 = fmaxf(m0, __shfl_xor(m0, 8));
    m1 = fmaxf(m1, __shfl_xor(m1, 1)); m1 = fmaxf(m1, __shfl_xor(m1, 2));
    m1 = fmaxf(m1, __shfl_xor(m1, 4)); m1 = fmaxf(m1, __shfl_xor(m1, 8));
    m2 = fmaxf(m2, __shfl_xor(m2, 1)); m2 = fmaxf(m2, __shfl_xor(m2, 2));
    m2 = fmaxf(m2, __shfl_xor(m2, 4)); m2 = fmaxf(m2, __shfl_xor(m2, 8));
    m3 = fmaxf(m3, __shfl_xor(m3, 1)); m3 = fmaxf(m3, __shfl_xor(m3, 2));
    m3 = fmaxf(m3, __shfl_xor(m3, 4)); m3 = fmaxf(m3, __shfl_xor(m3, 8));
    int rrow = rg * 16 + g * 4;
    if (q == 0) {
        red[(rrow + 0) * 4 + cg] = m0;
        red[(rrow + 1) * 4 + cg] = m1;
        red[(rrow + 2) * 4 + cg] = m2;
        red[(rrow + 3) * 4 + cg] = m3;
    }
    __syncthreads();
    {
        const float* r0 = &red[(rrow + 0) * 4];
        const float* r1 = &red[(rrow + 1) * 4];
        const float* r2 = &red[(rrow + 2) * 4];
        const float* r3 = &red[(rrow + 3) * 4];
        m0 = fmaxf(fmaxf(r0[0], r0[1]), fmaxf(r0[2], r0[3]));
        m1 = fmaxf(fmaxf(r1[0], r1[1]), fmaxf(r1[2], r1[3]));
        m2 = fmaxf(fmaxf(r2[0], r2[1]), fmaxf(r2[2], r2[3]));
        m3 = fmaxf(fmaxf(r3[0], r3[1]), fmaxf(r3[2], r3[3]));
    }
    __syncthreads();  // red reads done before sum-partial writes

    float s0 = 0.f, s1 = 0.f, s2 = 0.f, s3 = 0.f;
#define EX(n) { f32x4 tt = acc[n]; \
    tt[0] = __expf(tt[0] - m0); s0 += tt[0]; \
    tt[1] = __expf(tt[1] - m1); s1 += tt[1]; \
    tt[2] = __expf(tt[2] - m2); s2 += tt[2]; \
    tt[3] = __expf(tt[3] - m3); s3 += tt[3]; acc[n] = tt; }
    FOR32(EX)
#undef EX
    s0 += __shfl_xor(s0, 1); s0 += __shfl_xor(s0, 2);
    s0 += __shfl_xor(s0, 4); s0 += __shfl_xor(s0, 8);
    s1 += __shfl_xor(s1, 1); s1 += __shfl_xor(s1, 2);
    s1 += __shfl_xor(s1, 4); s1 += __shfl_xor(s1, 8);
    s2 += __shfl_xor(s2, 1); s2 += __shfl_xor(s2, 2);
    s2 += __shfl_xor(s2, 4); s2 += __shfl_xor(s2, 8);
    s3 += __shfl_xor(s3, 1); s3 += __shfl_xor(s3, 2);
    s3 += __shfl_xor(s3, 4); s3 += __shfl_xor(s3, 8);
    if (q == 0) {
        red[(rrow + 0) * 4 + cg] = s0;
        red[(rrow + 1) * 4 + cg] = s1;
        red[(rrow + 2) * 4 + cg] = s2;
        red[(rrow + 3) * 4 + cg] = s3;
    }
    __syncthreads();
    float iz0, iz1, iz2, iz3;
    {
        const float* r0 = &red[(rrow + 0) * 4];
        const float* r1 = &red[(rrow + 1) * 4];
        const float* r2 = &red[(rrow + 2) * 4];
        const float* r3 = &red[(rrow + 3) * 4];
        int rowg = row0 + rrow;
        iz0 = (rowg + 0 < N_NODES ? 1.f : 0.f) / (r0[0] + r0[1] + r0[2] + r0[3]);
        iz1 = (rowg + 1 < N_NODES ? 1.f : 0.f) / (r1[0] + r1[1] + r1[2] + r1[3]);
        iz2 = (rowg + 2 < N_NODES ? 1.f : 0.f) / (r2[0] + r2[1] + r2[2] + r2[3]);
        iz3 = (rowg + 3 < N_NODES ? 1.f : 0.f) / (r3[0] + r3[1] + r3[2] + r3[3]);
    }
#define CS(n) { f32x4 tt = acc[n]; \
    float cv = tt[0] * iz0 + tt[1] * iz1 + tt[2] * iz2 + tt[3] * iz3; \
    cv += __shfl_xor(cv, 16); cv += __shfl_xor(cv, 32); \
    if (g == 0) atomicAdd(&fpacc[colb + (n) * 16], cv); }
    FOR32(CS)
#undef CS
    __syncthreads();
    #pragma unroll
    for (int i = 0; i < 4; i++) {
        int cidx = t + i * 512;
        atomicAdd(&fp[cidx], fpacc[cidx]);
    }
}

// ---------------------------------------------------------------------------
// Launch
// ---------------------------------------------------------------------------
extern "C" void kernel_launch(void* const* d_in, const int* in_sizes, int n_in,
                              void* d_out, int out_size, void* d_ws, size_t ws_size,
                              hipStream_t stream) {
    const float* atoms  = (const float*)d_in[0];
    const int*   eidx   = (const int*)d_in[1];
    const float* init_w = (const float*)d_in[2];
    const float* init_b = (const float*)d_in[3];
    const float* hash_w = (const float*)d_in[4];
    const float* hash_b = (const float*)d_in[5];
    const float* soft_w = (const float*)d_in[6];
    const float* soft_b = (const float*)d_in[7];
    const float* gamma  = (const float*)d_in[8];
    const float* beta   = (const float*)d_in[9];
    float* fp = (float*)d_out;

    char* ws = (char*)d_ws;
    float* F      = (float*)ws; ws += (size_t)N_NODES * FEAT * 4;
    float* A      = (float*)ws; ws += (size_t)N_NODES * FEAT * 4;
    int*   counts = (int*)ws;   ws += (size_t)N_NODES * 4;
    int*   cursor = (int*)ws;   ws += (size_t)N_NODES * 4;
    int*   offs   = (int*)ws;   ws += (size_t)(N_NODES + 4) * 4;
    int*   csr    = (int*)ws;   ws += (size_t)N_EDGES * 4;
    float* stats  = (float*)ws; ws += (size_t)RADIUS * 2 * FEAT * 4;
    unsigned* WhiB = (unsigned*)ws; ws += (size_t)5 * FP_LEN * (FEAT / 2) * 4;
    unsigned* WloB = (unsigned*)ws; ws += (size_t)5 * FP_LEN * (FEAT / 2) * 4;
    unsigned* WhiH = (unsigned*)ws; ws += (size_t)RADIUS * FEAT * (FEAT / 2) * 4;
    unsigned* WloH = (unsigned*)ws; ws += (size_t)RADIUS * FEAT * (FEAT / 2) * 4;

    const int* src = eidx;
    const int* dst = eidx + N_EDGES;

    k_zero<<<256, 256, 0, stream>>>(fp, stats, counts, cursor);
    k_wsplit<<<dim3(32, 9), 256, 0, stream>>>(init_w, soft_w, hash_w,
                                              WhiB, WloB, WhiH, WloH);
    k_count<<<(N_EDGES + 255) / 256, 256, 0, stream>>>(dst, counts);
    k_scan<<<1, 1024, 0, stream>>>(counts, offs);
    k_fill<<<(N_EDGES + 255) / 256, 256, 0, stream>>>(src, dst, offs, cursor, csr);

    const int SMG = (N_NODES + 31) / 32;    // 1563
    const int HG  = (N_NODES + 63) / 64;    // 782

    k_smgemm_mfma<<<SMG, 512, 0, stream>>>(atoms, WhiB, WloB, init_b, fp);

    const float* feats = atoms;
    for (int l = 0; l < RADIUS; l++) {
        k_agg<<<N_NODES / 4, 256, 0, stream>>>(feats, A, offs, csr);
        float* ss = stats + l * 2 * FEAT;
        float* sq = ss + FEAT;
        k_hash_mfma<<<HG, 256, 0, stream>>>(
            A, WhiH + (size_t)l * FEAT * (FEAT / 2),
            WloH + (size_t)l * FEAT * (FEAT / 2),
            hash_b + (size_t)l * FEAT, F, ss, sq);
        k_finalize<<<1, FEAT, 0, stream>>>(ss, sq, gamma, beta);
        k_bnapply<<<(N_NODES * 32 + 255) / 256, 256, 0, stream>>>(F, ss, sq);
        k_smgemm_mfma<<<SMG, 512, 0, stream>>>(
            F, WhiB + (size_t)(1 + l) * FP_LEN * (FEAT / 2),
            WloB + (size_t)(1 + l) * FP_LEN * (FEAT / 2),
            soft_b + (size_t)l * FP_LEN, fp);
        feats = F;
    }
}

// Round 12
// 3226.703 us; speedup vs baseline: 1.3130x; 1.3103x over previous
//
#include <hip/hip_runtime.h>
#include <hip/hip_bf16.h>

#define N_NODES 50000
#define FEAT    128
#define FP_LEN  2048
#define RADIUS  4
#define N_EDGES 600000
#define BN_EPS  1e-5f

typedef __attribute__((ext_vector_type(8))) short bh8;   // 8 bf16 = 4 VGPR
typedef __attribute__((ext_vector_type(4))) float f32x4;

#define FOR8(M)  M(0) M(1) M(2) M(3) M(4) M(5) M(6) M(7)
#define FOR16(M) M(0) M(1) M(2) M(3) M(4) M(5) M(6) M(7) M(8) M(9) M(10) M(11) \
                 M(12) M(13) M(14) M(15)

// B-stream pipeline macros (textually reference BH, BL, base, ah, al, acc)
#define LD1(buf, i, n) { buf[2*(i)] = BH[base + (n) * 256]; \
                         buf[2*(i)+1] = BL[base + (n) * 256]; }
#define MF1(buf, i, n) { \
    bh8 bhf = __builtin_bit_cast(bh8, buf[2*(i)]); \
    bh8 blf = __builtin_bit_cast(bh8, buf[2*(i)+1]); \
    f32x4 t = acc[n]; \
    t = __builtin_amdgcn_mfma_f32_16x16x32_bf16(ah, bhf, t, 0, 0, 0); \
    t = __builtin_amdgcn_mfma_f32_16x16x32_bf16(ah, blf, t, 0, 0, 0); \
    t = __builtin_amdgcn_mfma_f32_16x16x32_bf16(al, bhf, t, 0, 0, 0); \
    acc[n] = t; }
// 2-subtile chunk variants (chunk c covers subtiles 2c, 2c+1); buf = uint4[4]
#define LDC2(buf, c) LD1(buf, 0, (c)*2) LD1(buf, 1, (c)*2+1)
#define MFC2(buf, c) MF1(buf, 0, (c)*2) MF1(buf, 1, (c)*2+1)
// 4-subtile chunk variants for k_hash_mfma; buf = uint4[8]
#define LDC(buf, c) LD1(buf, 0, (c)*4) LD1(buf, 1, (c)*4+1) \
                    LD1(buf, 2, (c)*4+2) LD1(buf, 3, (c)*4+3)
#define MFC(buf, c) MF1(buf, 0, (c)*4) MF1(buf, 1, (c)*4+1) \
                    MF1(buf, 2, (c)*4+2) MF1(buf, 3, (c)*4+3)

// round-to-nearest-even fp32 -> bf16 (returns low 16 bits)
__device__ __forceinline__ unsigned bf16_rne(float x) {
    unsigned u = __float_as_uint(x);
    return (u + 0x7fffu + ((u >> 16) & 1u)) >> 16;
}

// split two floats into packed-pair hi/lo bf16 dwords (elem0 = low half)
__device__ __forceinline__ void split2(float x0, float x1, unsigned& hi, unsigned& lo) {
    unsigned h0 = bf16_rne(x0), h1 = bf16_rne(x1);
    float r0 = x0 - __uint_as_float(h0 << 16);
    float r1 = x1 - __uint_as_float(h1 << 16);
    hi = h0 | (h1 << 16);
    lo = bf16_rne(r0) | (bf16_rne(r1) << 16);
}

// Stage X[row0..row0+ROWS) x 128 fp32 -> LDS split bf16 hi/lo, XOR-swizzled
// (byte ^= (row&7)<<4 within each 256B row) for conflict-free b128 frag reads.
template <int ROWS, int NT>
__device__ __forceinline__ void stage_split(const float* __restrict__ X, int row0,
                                            unsigned short* Ahi, unsigned short* Alo,
                                            int t) {
    const int NF4 = ROWS * 32;  // float4 count
    const float4* X4 = (const float4*)(X + (size_t)row0 * FEAT);
    #pragma unroll
    for (int f = t; f < NF4; f += NT) {
        int row = f >> 5, kq = f & 31;  // k = kq*4
        float4 v = make_float4(0.f, 0.f, 0.f, 0.f);
        if (row0 + row < N_NODES) v = X4[f];
        unsigned h0, l0, h1, l1;
        split2(v.x, v.y, h0, l0);
        split2(v.z, v.w, h1, l1);
        int boff = (kq * 8) ^ ((row & 7) << 4);
        unsigned* dh = (unsigned*)((char*)Ahi + row * 256 + boff);
        unsigned* dl = (unsigned*)((char*)Alo + row * 256 + boff);
        dh[0] = h0; dh[1] = h1;
        dl[0] = l0; dl[1] = l1;
    }
}

// ---------------------------------------------------------------------------
// Zero accumulators.
// ---------------------------------------------------------------------------
__global__ __launch_bounds__(256) void k_zero(float* fp, float* stats,
                                              int* counts, int* cursor) {
    int i = blockIdx.x * blockDim.x + threadIdx.x;
    int n = gridDim.x * blockDim.x;
    for (int j = i; j < FP_LEN; j += n) fp[j] = 0.f;
    for (int j = i; j < RADIUS * 2 * FEAT; j += n) stats[j] = 0.f;
    for (int j = i; j < N_NODES; j += n) { counts[j] = 0; cursor[j] = 0; }
}

// ---------------------------------------------------------------------------
// W split+transpose: fp32 [128][N] -> hi/lo bf16 [N][128] (K-contiguous).
// ---------------------------------------------------------------------------
__global__ __launch_bounds__(256) void k_wsplit(
    const float* __restrict__ init_w, const float* __restrict__ soft_w,
    const float* __restrict__ hash_w,
    unsigned* __restrict__ WhiB, unsigned* __restrict__ WloB,
    unsigned* __restrict__ WhiH, unsigned* __restrict__ WloH) {
    __shared__ float Tl[128][65];
    int t = threadIdx.x;
    int y = blockIdx.y;
    const float* W;
    unsigned *Oh, *Ol;
    int N;
    if (y < 5) {
        N = FP_LEN;
        W = (y == 0) ? init_w : soft_w + (size_t)(y - 1) * FEAT * FP_LEN;
        Oh = WhiB + (size_t)y * FP_LEN * (FEAT / 2);
        Ol = WloB + (size_t)y * FP_LEN * (FEAT / 2);
    } else {
        if (blockIdx.x >= 2) return;  // uniform per block
        N = FEAT;
        W = hash_w + (size_t)(y - 5) * FEAT * FEAT;
        Oh = WhiH + (size_t)(y - 5) * FEAT * (FEAT / 2);
        Ol = WloH + (size_t)(y - 5) * FEAT * (FEAT / 2);
    }
    int n0 = blockIdx.x * 64;
    #pragma unroll
    for (int i = 0; i < 8; i++) {
        int f = t + i * 256;  // 0..2047
        int k = f >> 4, nq = f & 15;
        float4 v = *(const float4*)(W + (size_t)k * N + n0 + nq * 4);
        Tl[k][nq * 4 + 0] = v.x; Tl[k][nq * 4 + 1] = v.y;
        Tl[k][nq * 4 + 2] = v.z; Tl[k][nq * 4 + 3] = v.w;
    }
    __syncthreads();
    int nl = t >> 2, kq = t & 3;  // col n0+nl, k-range kq*32..+31
    unsigned hi[16], lo[16];
    #pragma unroll
    for (int d = 0; d < 16; d++) {
        float x0 = Tl[kq * 32 + 2 * d][nl];
        float x1 = Tl[kq * 32 + 2 * d + 1][nl];
        split2(x0, x1, hi[d], lo[d]);
    }
    size_t col = n0 + nl;
    uint4* H = (uint4*)Oh + col * 16 + kq * 4;
    uint4* L = (uint4*)Ol + col * 16 + kq * 4;
    #pragma unroll
    for (int j = 0; j < 4; j++) {
        H[j] = make_uint4(hi[4 * j], hi[4 * j + 1], hi[4 * j + 2], hi[4 * j + 3]);
        L[j] = make_uint4(lo[4 * j], lo[4 * j + 1], lo[4 * j + 2], lo[4 * j + 3]);
    }
}

// ---------------------------------------------------------------------------
// CSR build.
// ---------------------------------------------------------------------------
__global__ __launch_bounds__(256) void k_count(const int* __restrict__ dst,
                                               int* __restrict__ counts) {
    int e = blockIdx.x * 256 + threadIdx.x;
    if (e < N_EDGES) {
        unsigned d = (unsigned)dst[e];
        if (d < N_NODES) atomicAdd(&counts[d], 1);
    }
}

__global__ __launch_bounds__(1024) void k_scan(const int* __restrict__ counts,
                                               int* __restrict__ offs) {
    __shared__ int part[1024];
    int tid = threadIdx.x;
    const int chunk = (N_NODES + 1023) / 1024;
    int lo = tid * chunk;
    int hi = min(lo + chunk, N_NODES);
    int s = 0;
    for (int i = lo; i < hi; i++) s += counts[i];
    part[tid] = s;
    __syncthreads();
    for (int off = 1; off < 1024; off <<= 1) {
        int v = (tid >= off) ? part[tid - off] : 0;
        __syncthreads();
        part[tid] += v;
        __syncthreads();
    }
    int run = part[tid] - s;
    for (int i = lo; i < hi; i++) { offs[i] = run; run += counts[i]; }
    if (lo < N_NODES && hi == N_NODES) offs[N_NODES] = run;
}

__global__ __launch_bounds__(256) void k_fill(const int* __restrict__ src,
                                              const int* __restrict__ dst,
                                              const int* __restrict__ offs,
                                              int* __restrict__ cursor,
                                              int* __restrict__ csr) {
    int e = blockIdx.x * 256 + threadIdx.x;
    if (e < N_EDGES) {
        unsigned d = (unsigned)dst[e];
        unsigned s = (unsigned)src[e];
        if (d < N_NODES && s < N_NODES) {
            int p = atomicAdd(&cursor[d], 1);
            csr[offs[d] + p] = (int)s;
        }
    }
}

// ---------------------------------------------------------------------------
// Aggregation: agg[i] = feats[i] + sum_{e: dst==i} feats[src_e]
// ---------------------------------------------------------------------------
__global__ __launch_bounds__(256) void k_agg(const float* __restrict__ feats,
                                             float* __restrict__ agg,
                                             const int* __restrict__ offs,
                                             const int* __restrict__ csr) {
    int node = blockIdx.x * 4 + (threadIdx.x >> 6);
    int lane = threadIdx.x & 63;
    const float2* f2 = (const float2*)feats;
    float2 acc = f2[node * 64 + lane];
    int j0 = offs[node], j1 = offs[node + 1];
    for (int j = j0; j < j1; j++) {
        int s = csr[j];
        float2 v = f2[s * 64 + lane];
        acc.x += v.x; acc.y += v.y;
    }
    ((float2*)agg)[node * 64 + lane] = acc;
}

// ---------------------------------------------------------------------------
// Hash layer via bf16x3 MFMA: h = relu(agg @ W + b) + fused BN column stats.
// Block: 64 rows x 128 cols, 4 waves (wave = 16 rows x 128 cols), 36 KB LDS.
// ---------------------------------------------------------------------------
__global__ __launch_bounds__(256, 2) void k_hash_mfma(
    const float* __restrict__ Xagg,
    const unsigned* __restrict__ WhiT, const unsigned* __restrict__ WloT,
    const float* __restrict__ bias, float* __restrict__ h,
    float* __restrict__ stat_sum, float* __restrict__ stat_sq) {
    __shared__ unsigned short Ahi[64 * FEAT];   // 16 KB
    __shared__ unsigned short Alo[64 * FEAT];   // 16 KB
    __shared__ float colred[2][4][FEAT];        // 4 KB

    int t = threadIdx.x;
    int row0 = blockIdx.x * 64;
    stage_split<64, 256>(Xagg, row0, Ahi, Alo, t);
    __syncthreads();

    int wave = t >> 6, lane = t & 63;
    int g = lane >> 4, q = lane & 15;

    f32x4 acc[8];
#define ZH(n) acc[n] = (f32x4){0.f, 0.f, 0.f, 0.f};
    FOR8(ZH)
#undef ZH

    int arow = wave * 16 + q;
    const uint4* BH = (const uint4*)WhiT;
    const uint4* BL = (const uint4*)WloT;
    uint4 bufA[8], bufB[8];

    for (int s = 0; s < 4; s++) {
        int aoff = arow * 256 + (((s * 64) + (g * 16)) ^ ((arow & 7) << 4));
        bh8 ah = *(const bh8*)((const char*)Ahi + aoff);
        bh8 al = *(const bh8*)((const char*)Alo + aoff);
        int base = q * 16 + g + s * 4;
        LDC(bufA, 0) LDC(bufB, 1)
        MFC(bufA, 0)
        MFC(bufB, 1)
    }

    // epilogue: bias + relu + mask, store h, column stats
    int rbase = row0 + wave * 16 + g * 4;
    float vm0 = (rbase + 0 < N_NODES) ? 1.f : 0.f;
    float vm1 = (rbase + 1 < N_NODES) ? 1.f : 0.f;
    float vm2 = (rbase + 2 < N_NODES) ? 1.f : 0.f;
    float vm3 = (rbase + 3 < N_NODES) ? 1.f : 0.f;
#define EH(n) { int col = (n) * 16 + q; float b = bias[col]; f32x4 tt = acc[n]; \
    float v0 = fmaxf(tt[0] + b, 0.f) * vm0; \
    float v1 = fmaxf(tt[1] + b, 0.f) * vm1; \
    float v2 = fmaxf(tt[2] + b, 0.f) * vm2; \
    float v3 = fmaxf(tt[3] + b, 0.f) * vm3; \
    if (vm0 != 0.f) h[(size_t)(rbase + 0) * FEAT + col] = v0; \
    if (vm1 != 0.f) h[(size_t)(rbase + 1) * FEAT + col] = v1; \
    if (vm2 != 0.f) h[(size_t)(rbase + 2) * FEAT + col] = v2; \
    if (vm3 != 0.f) h[(size_t)(rbase + 3) * FEAT + col] = v3; \
    float cs = v0 + v1 + v2 + v3; \
    float cq = v0 * v0 + v1 * v1 + v2 * v2 + v3 * v3; \
    cs += __shfl_xor(cs, 16); cs += __shfl_xor(cs, 32); \
    cq += __shfl_xor(cq, 16); cq += __shfl_xor(cq, 32); \
    if (g == 0) { colred[0][wave][col] = cs; colred[1][wave][col] = cq; } }
    FOR8(EH)
#undef EH
    __syncthreads();
    if (t < FEAT) {
        float s = 0.f, qq = 0.f;
        #pragma unroll
        for (int w2 = 0; w2 < 4; w2++) { s += colred[0][w2][t]; qq += colred[1][w2][t]; }
        atomicAdd(&stat_sum[t], s);
        atomicAdd(&stat_sq[t], qq);
    }
}

// ---------------------------------------------------------------------------
// BN finalize + apply.
// ---------------------------------------------------------------------------
__global__ void k_finalize(float* stat_sum, float* stat_sq,
                           const float* __restrict__ gamma,
                           const float* __restrict__ beta) {
    int c = threadIdx.x;
    float mu = stat_sum[c] * (1.f / N_NODES);
    float var = stat_sq[c] * (1.f / N_NODES) - mu * mu;
    float sc = gamma[c] * rsqrtf(var + BN_EPS);
    float sh = beta[c] - mu * sc;
    stat_sum[c] = sc;
    stat_sq[c] = sh;
}

__global__ __launch_bounds__(256) void k_bnapply(float* __restrict__ h,
                                                 const float* __restrict__ scale,
                                                 const float* __restrict__ shift) {
    int i = blockIdx.x * 256 + threadIdx.x;
    const float4* sc4 = (const float4*)scale;
    const float4* sh4 = (const float4*)shift;
    if (i < N_NODES * 32) {
        float4 v = ((float4*)h)[i];
        int cb = i & 31;
        float4 s = sc4[cb], b = sh4[cb];
        v.x = v.x * s.x + b.x;
        v.y = v.y * s.y + b.y;
        v.z = v.z * s.z + b.z;
        v.w = v.w * s.w + b.w;
        ((float4*)h)[i] = v;
    }
}

// ---------------------------------------------------------------------------
// Fused softmax-sum GEMM via bf16x3 MFMA.
// Block: 32 rows x 2048 cols, 1024 threads = 16 waves = 2 rowgrp x 8 colgrp.
// Wave: 16 rows x 256 cols = 16 subtiles -> acc[16] = 64 VGPR.
// Register budget DESIGNED for the observed 128-VGPR cap (rounds 5/9/11
// all measured VGPR_Count=128 regardless of __launch_bounds__): acc 64 +
// 2x2-subtile double-buffer 32 + A-frags 8 + addressing ~15 = ~120 <= 128.
// At 1024 thr the cap is also architecturally exact (16 waves/block = 4
// waves/SIMD x 128 = 512-reg SIMD pool). No spill; 4 waves/SIMD TLP.
// C layout (m89): col = cg*256 + n*16 + q, row = g*4 + reg.
// ---------------------------------------------------------------------------
__global__ __launch_bounds__(1024) void k_smgemm_mfma(
    const float* __restrict__ X,
    const unsigned* __restrict__ WhiT, const unsigned* __restrict__ WloT,
    const float* __restrict__ bias, float* __restrict__ fp) {
    __shared__ unsigned short Ahi[32 * FEAT];  // 8 KB
    __shared__ unsigned short Alo[32 * FEAT];  // 8 KB
    __shared__ float fpacc[FP_LEN];            // 8 KB
    __shared__ float red[32 * 8];              // 1 KB

    int t = threadIdx.x;
    int row0 = blockIdx.x * 32;

    fpacc[t] = 0.f;
    fpacc[t + 1024] = 0.f;

    stage_split<32, 1024>(X, row0, Ahi, Alo, t);
    __syncthreads();

    int wave = t >> 6, lane = t & 63;
    int rg = wave >> 3, cg = wave & 7;
    int g = lane >> 4, q = lane & 15;

    f32x4 acc[16];
#define ZZ(n) acc[n] = (f32x4){0.f, 0.f, 0.f, 0.f};
    FOR16(ZZ)
#undef ZZ

    int arow = rg * 16 + q;
    const uint4* BH = (const uint4*)WhiT;
    const uint4* BL = (const uint4*)WloT;
    int bbase = (cg * 256 + q) * 16 + g;  // [col][k] uint4 units; +n*256, +s*4
    uint4 bufA[4], bufB[4];

    for (int s = 0; s < 4; s++) {
        int aoff = arow * 256 + (((s * 64) + (g * 16)) ^ ((arow & 7) << 4));
        bh8 ah = *(const bh8*)((const char*)Ahi + aoff);
        bh8 al = *(const bh8*)((const char*)Alo + aoff);
        int base = bbase + s * 4;
        LDC2(bufA, 0) LDC2(bufB, 1)
        MFC2(bufA, 0) LDC2(bufA, 2)
        MFC2(bufB, 1) LDC2(bufB, 3)
        MFC2(bufA, 2) LDC2(bufA, 4)
        MFC2(bufB, 3) LDC2(bufB, 5)
        MFC2(bufA, 4) LDC2(bufA, 6)
        MFC2(bufB, 5) LDC2(bufB, 7)
        MFC2(bufA, 6)
        MFC2(bufB, 7)
    }

    // ---- softmax epilogue (logits fully in registers) ----
    int colb = cg * 256 + q;
    float m0 = -3.4e38f, m1 = -3.4e38f, m2 = -3.4e38f, m3 = -3.4e38f;
#define BM(n) { float b = bias[colb + (n) * 16]; f32x4 tt = acc[n]; \
    tt[0] += b; tt[1] += b; tt[2] += b; tt[3] += b; \
    m0 = fmaxf(m0, tt[0]); m1 = fmaxf(m1, tt[1]); \
    m2 = fmaxf(m2, tt[2]); m3 = fmaxf(m3, tt[3]); acc[n] = tt; }
    FOR16(BM)
#undef BM
    // row max across q-lanes (cols), then across the 8 col-group waves
    m0 = fmaxf(m0, __shfl_xor(m0, 1)); m0 = fmaxf(m0, __shfl_xor(m0, 2));
    m0 = fmaxf(m0, __shfl_xor(m0, 4)); m0 = fmaxf(m0, __shfl_xor(m0, 8));
    m1 = fmaxf(m1, __shfl_xor(m1, 1)); m1 = fmaxf(m1, __shfl_xor(m1, 2));
    m1 = fmaxf(m1, __shfl_xor(m1, 4)); m1 = fmaxf(m1, __shfl_xor(m1, 8));
    m2 = fmaxf(m2, __shfl_xor(m2, 1)); m2 = fmaxf(m2, __shfl_xor(m2, 2));
    m2 = fmaxf(m2, __shfl_xor(m2, 4)); m2 = fmaxf(m2, __shfl_xor(m2, 8));
    m3 = fmaxf(m3, __shfl_xor(m3, 1)); m3 = fmaxf(m3, __shfl_xor(m3, 2));
    m3 = fmaxf(m3, __shfl_xor(m3, 4)); m3 = fmaxf(m3, __shfl_xor(m3, 8));
    int rrow = rg * 16 + g * 4;
    if (q == 0) {
        red[(rrow + 0) * 8 + cg] = m0;
        red[(rrow + 1) * 8 + cg] = m1;
        red[(rrow + 2) * 8 + cg] = m2;
        red[(rrow + 3) * 8 + cg] = m3;
    }
    __syncthreads();
    {
        const float* r0 = &red[(rrow + 0) * 8];
        const float* r1 = &red[(rrow + 1) * 8];
        const float* r2 = &red[(rrow + 2) * 8];
        const float* r3 = &red[(rrow + 3) * 8];
        m0 = fmaxf(fmaxf(fmaxf(r0[0], r0[1]), fmaxf(r0[2], r0[3])),
                   fmaxf(fmaxf(r0[4], r0[5]), fmaxf(r0[6], r0[7])));
        m1 = fmaxf(fmaxf(fmaxf(r1[0], r1[1]), fmaxf(r1[2], r1[3])),
                   fmaxf(fmaxf(r1[4], r1[5]), fmaxf(r1[6], r1[7])));
        m2 = fmaxf(fmaxf(fmaxf(r2[0], r2[1]), fmaxf(r2[2], r2[3])),
                   fmaxf(fmaxf(r2[4], r2[5]), fmaxf(r2[6], r2[7])));
        m3 = fmaxf(fmaxf(fmaxf(r3[0], r3[1]), fmaxf(r3[2], r3[3])),
                   fmaxf(fmaxf(r3[4], r3[5]), fmaxf(r3[6], r3[7])));
    }
    __syncthreads();  // red reads done before sum-partial writes

    float s0 = 0.f, s1 = 0.f, s2 = 0.f, s3 = 0.f;
#define EX(n) { f32x4 tt = acc[n]; \
    tt[0] = __expf(tt[0] - m0); s0 += tt[0]; \
    tt[1] = __expf(tt[1] - m1); s1 += tt[1]; \
    tt[2] = __expf(tt[2] - m2); s2 += tt[2]; \
    tt[3] = __expf(tt[3] - m3); s3 += tt[3]; acc[n] = tt; }
    FOR16(EX)
#undef EX
    s0 += __shfl_xor(s0, 1); s0 += __shfl_xor(s0, 2);
    s0 += __shfl_xor(s0, 4); s0 += __shfl_xor(s0, 8);
    s1 += __shfl_xor(s1, 1); s1 += __shfl_xor(s1, 2);
    s1 += __shfl_xor(s1, 4); s1 += __shfl_xor(s1, 8);
    s2 += __shfl_xor(s2, 1); s2 += __shfl_xor(s2, 2);
    s2 += __shfl_xor(s2, 4); s2 += __shfl_xor(s2, 8);
    s3 += __shfl_xor(s3, 1); s3 += __shfl_xor(s3, 2);
    s3 += __shfl_xor(s3, 4); s3 += __shfl_xor(s3, 8);
    if (q == 0) {
        red[(rrow + 0) * 8 + cg] = s0;
        red[(rrow + 1) * 8 + cg] = s1;
        red[(rrow + 2) * 8 + cg] = s2;
        red[(rrow + 3) * 8 + cg] = s3;
    }
    __syncthreads();
    float iz0, iz1, iz2, iz3;
    {
        const float* r0 = &red[(rrow + 0) * 8];
        const float* r1 = &red[(rrow + 1) * 8];
        const float* r2 = &red[(rrow + 2) * 8];
        const float* r3 = &red[(rrow + 3) * 8];
        int rowg = row0 + rrow;
        float Z0 = r0[0] + r0[1] + r0[2] + r0[3] + r0[4] + r0[5] + r0[6] + r0[7];
        float Z1 = r1[0] + r1[1] + r1[2] + r1[3] + r1[4] + r1[5] + r1[6] + r1[7];
        float Z2 = r2[0] + r2[1] + r2[2] + r2[3] + r2[4] + r2[5] + r2[6] + r2[7];
        float Z3 = r3[0] + r3[1] + r3[2] + r3[3] + r3[4] + r3[5] + r3[6] + r3[7];
        iz0 = (rowg + 0 < N_NODES ? 1.f : 0.f) / Z0;
        iz1 = (rowg + 1 < N_NODES ? 1.f : 0.f) / Z1;
        iz2 = (rowg + 2 < N_NODES ? 1.f : 0.f) / Z2;
        iz3 = (rowg + 3 < N_NODES ? 1.f : 0.f) / Z3;
    }
#define CS(n) { f32x4 tt = acc[n]; \
    float cv = tt[0] * iz0 + tt[1] * iz1 + tt[2] * iz2 + tt[3] * iz3; \
    cv += __shfl_xor(cv, 16); cv += __shfl_xor(cv, 32); \
    if (g == 0) atomicAdd(&fpacc[colb + (n) * 16], cv); }
    FOR16(CS)
#undef CS
    __syncthreads();
    atomicAdd(&fp[t], fpacc[t]);
    atomicAdd(&fp[t + 1024], fpacc[t + 1024]);
}

// ---------------------------------------------------------------------------
// Launch
// ---------------------------------------------------------------------------
extern "C" void kernel_launch(void* const* d_in, const int* in_sizes, int n_in,
                              void* d_out, int out_size, void* d_ws, size_t ws_size,
                              hipStream_t stream) {
    const float* atoms  = (const float*)d_in[0];
    const int*   eidx   = (const int*)d_in[1];
    const float* init_w = (const float*)d_in[2];
    const float* init_b = (const float*)d_in[3];
    const float* hash_w = (const float*)d_in[4];
    const float* hash_b = (const float*)d_in[5];
    const float* soft_w = (const float*)d_in[6];
    const float* soft_b = (const float*)d_in[7];
    const float* gamma  = (const float*)d_in[8];
    const float* beta   = (const float*)d_in[9];
    float* fp = (float*)d_out;

    char* ws = (char*)d_ws;
    float* F      = (float*)ws; ws += (size_t)N_NODES * FEAT * 4;
    float* A      = (float*)ws; ws += (size_t)N_NODES * FEAT * 4;
    int*   counts = (int*)ws;   ws += (size_t)N_NODES * 4;
    int*   cursor = (int*)ws;   ws += (size_t)N_NODES * 4;
    int*   offs   = (int*)ws;   ws += (size_t)(N_NODES + 4) * 4;
    int*   csr    = (int*)ws;   ws += (size_t)N_EDGES * 4;
    float* stats  = (float*)ws; ws += (size_t)RADIUS * 2 * FEAT * 4;
    unsigned* WhiB = (unsigned*)ws; ws += (size_t)5 * FP_LEN * (FEAT / 2) * 4;
    unsigned* WloB = (unsigned*)ws; ws += (size_t)5 * FP_LEN * (FEAT / 2) * 4;
    unsigned* WhiH = (unsigned*)ws; ws += (size_t)RADIUS * FEAT * (FEAT / 2) * 4;
    unsigned* WloH = (unsigned*)ws; ws += (size_t)RADIUS * FEAT * (FEAT / 2) * 4;

    const int* src = eidx;
    const int* dst = eidx + N_EDGES;

    k_zero<<<256, 256, 0, stream>>>(fp, stats, counts, cursor);
    k_wsplit<<<dim3(32, 9), 256, 0, stream>>>(init_w, soft_w, hash_w,
                                              WhiB, WloB, WhiH, WloH);
    k_count<<<(N_EDGES + 255) / 256, 256, 0, stream>>>(dst, counts);
    k_scan<<<1, 1024, 0, stream>>>(counts, offs);
    k_fill<<<(N_EDGES + 255) / 256, 256, 0, stream>>>(src, dst, offs, cursor, csr);

    const int SMG = (N_NODES + 31) / 32;    // 1563
    const int HG  = (N_NODES + 63) / 64;    // 782

    k_smgemm_mfma<<<SMG, 1024, 0, stream>>>(atoms, WhiB, WloB, init_b, fp);

    const float* feats = atoms;
    for (int l = 0; l < RADIUS; l++) {
        k_agg<<<N_NODES / 4, 256, 0, stream>>>(feats, A, offs, csr);
        float* ss = stats + l * 2 * FEAT;
        float* sq = ss + FEAT;
        k_hash_mfma<<<HG, 256, 0, stream>>>(
            A, WhiH + (size_t)l * FEAT * (FEAT / 2),
            WloH + (size_t)l * FEAT * (FEAT / 2),
            hash_b + (size_t)l * FEAT, F, ss, sq);
        k_finalize<<<1, FEAT, 0, stream>>>(ss, sq, gamma, beta);
        k_bnapply<<<(N_NODES * 32 + 255) / 256, 256, 0, stream>>>(F, ss, sq);
        k_smgemm_mfma<<<SMG, 1024, 0, stream>>>(
            F, WhiB + (size_t)(1 + l) * FP_LEN * (FEAT / 2),
            WloB + (size_t)(1 + l) * FP_LEN * (FEAT / 2),
            soft_b + (size_t)l * FP_LEN, fp);
        feats = F;
    }
}